// Round 8
// baseline (1500.524 us; speedup 1.0000x reference)
//
#include <hip/hip_runtime.h>
#include <stdint.h>

#define N_NODES 50000
#define DIM_MEM 512
#define DIM_MSG 1280
#define N_MSG   100000

typedef __attribute__((ext_vector_type(8))) short bf16x8;
typedef __attribute__((ext_vector_type(4))) float f32x4;

template <int N> struct ic { static constexpr int v = N; };

// counted vmcnt wait + scheduler fence (rule #18)
#define WAITV(n) do { asm volatile("s_waitcnt vmcnt(" #n ")" ::: "memory"); \
                      __builtin_amdgcn_sched_barrier(0); } while (0)

__device__ __forceinline__ unsigned short f2bf(float f) {
  union { float f; uint32_t u; } v; v.f = f;
  uint32_t u = v.u;
  u += 0x7fffu + ((u >> 16) & 1u);   // round-to-nearest-even
  return (unsigned short)(u >> 16);
}

// ---------------- kernel 1: segment mean (seg_ids sorted) ----------------
__global__ __launch_bounds__(64) void k_segmean(
    const float* __restrict__ msg, const int* __restrict__ seg,
    unsigned short* __restrict__ means, int* __restrict__ counts)
{
  int node = blockIdx.x;
  int lane = threadIdx.x;

  int lo = 0, hi = N_MSG;
  while (lo < hi) { int m = (lo + hi) >> 1; if (seg[m] < node) lo = m + 1; else hi = m; }
  int start = lo;
  hi = N_MSG;
  while (lo < hi) { int m = (lo + hi) >> 1; if (seg[m] < node + 1) lo = m + 1; else hi = m; }
  int end = lo;
  int cnt = end - start;
  if (lane == 0) counts[node] = cnt;

  float4 s[5];
#pragma unroll
  for (int j = 0; j < 5; j++) s[j] = make_float4(0.f, 0.f, 0.f, 0.f);
  const float4* m4 = (const float4*)msg;   // 320 float4 per row
  for (int r = start; r < end; r++) {
#pragma unroll
    for (int j = 0; j < 5; j++) {
      float4 v = m4[r * 320 + j * 64 + lane];
      s[j].x += v.x; s[j].y += v.y; s[j].z += v.z; s[j].w += v.w;
    }
  }
  float inv = (cnt > 0) ? 1.0f / (float)cnt : 0.0f;
  ushort4* o4 = (ushort4*)means;
#pragma unroll
  for (int j = 0; j < 5; j++) {
    ushort4 o;
    o.x = f2bf(s[j].x * inv); o.y = f2bf(s[j].y * inv);
    o.z = f2bf(s[j].z * inv); o.w = f2bf(s[j].w * inv);
    o4[node * 320 + j * 64 + lane] = o;
  }
}

// ---------------- kernel 2: f32 -> bf16 cast ----------------
__global__ __launch_bounds__(256) void k_cvt(
    const float* __restrict__ in, unsigned short* __restrict__ out, int n4)
{
  int i = blockIdx.x * 256 + threadIdx.x;
  if (i >= n4) return;
  float4 v = ((const float4*)in)[i];
  ushort4 o;
  o.x = f2bf(v.x); o.y = f2bf(v.y); o.z = f2bf(v.z); o.w = f2bf(v.w);
  ((ushort4*)out)[i] = o;
}

// ---------------- kernel 3: fused GEMM (4 strips) + GRU epilogue ----------------
// Big-tile + dbuf counted-vmcnt pipeline:
//   block = 256 rows x 64 out-cols, 512 threads / 8 waves (4 row-grp x 2 col-grp)
//   wave  = 64r x 32c per strip; acc[4][2][4strips] = 128 f32/lane (AGPR)
//   LDS   = dbuf x (A 256x64 = 32 KB + B 192x64 = 24 KB) = 112 KB, 1 block/CU
// Per wave-chunk: 7 global_load_lds, 20 ds_read_b128, 48 MFMA (39 kFLOP/read;
// 112 FLOP per staged byte -> LDS floor ~70 us vs R7's 223 us).
// Schedule: stage(c+1) issued BEFORE waiting chunk c (WAITV(7), never 0 in
// loop); trailing barrier = WAR for buffer overwrite. T5 setprio around MFMA
// (2 waves/SIMD role diversity).
// Layout (R6-proven): row-major [row][64k], XOR swizzle granule ^= (row&7);
// staging source permutes k-granule (csrc = (lane&7)^lrow) -> fully coalesced.
// 28 K-chunks: 0..19 = means@W_ih^T (K=1280), 20..27 = memb@W_hh^T (K=512).
__global__ __launch_bounds__(512) void k_gru(
    const unsigned short* __restrict__ means, const unsigned short* __restrict__ memb,
    const unsigned short* __restrict__ wih,   const unsigned short* __restrict__ whh,
    const float* __restrict__ b_ih, const float* __restrict__ b_hh,
    const float* __restrict__ memory, const int* __restrict__ counts,
    float* __restrict__ out)
{
  __shared__ unsigned short Al[2][256 * 64];   // 2 x 32 KB
  __shared__ unsigned short Bl[2][192 * 64];   // 2 x 24 KB

  int tid = threadIdx.x;
  int lane = tid & 63, wid = tid >> 6;        // 8 waves
  int wr = wid >> 1, wc = wid & 1;            // 4 row-groups x 2 col-groups
  int row0 = blockIdx.y * 256;
  int c0 = blockIdx.x * 64;

  f32x4 acc[4][2][4];                          // [row-frag][col-frag][strip]
#pragma unroll
  for (int f = 0; f < 4; f++)
#pragma unroll
    for (int cf = 0; cf < 2; cf++)
#pragma unroll
      for (int s = 0; s < 4; s++) acc[f][cf][s] = (f32x4)(0.f);

  int lrow = lane >> 3;                        // row-within-8 for staging
  int csrc = (lane & 7) ^ lrow;                // inverse-swizzled source k-granule

  // stage chunk c into dbuf pb (4 A-loads + 3 B-loads per wave)
  auto stage = [&](int c, int pb) {
    const unsigned short* Ag; const unsigned short* Bg; int ld, k0;
    if (c < 20) { Ag = means; Bg = wih; ld = DIM_MSG; k0 = c * 64; }
    else        { Ag = memb;  Bg = whh; ld = DIM_MEM; k0 = (c - 20) * 64; }
#pragma unroll
    for (int i = 0; i < 4; i++) {              // A: 8 rows per load
      int rbase = (wid * 4 + i) * 8;           // 0..255
      int grow = row0 + rbase + lrow; if (grow > N_NODES - 1) grow = N_NODES - 1;
      const unsigned short* src = Ag + (size_t)grow * ld + k0 + csrc * 8;
      __builtin_amdgcn_global_load_lds(
          (const __attribute__((address_space(1))) void*)src,
          (__attribute__((address_space(3))) void*)&Al[pb][rbase * 64],
          16, 0, 0);
    }
#pragma unroll
    for (int i = 0; i < 3; i++) {              // B: 8 gate-cols per load
      int gbase = (wid * 3 + i) * 8;           // 0..191
      int gcol = gbase + lrow;
      int st = gcol >> 6, col = gcol & 63;
      const unsigned short* src = Bg + (size_t)(st * 512 + c0 + col) * ld + k0 + csrc * 8;
      __builtin_amdgcn_global_load_lds(
          (const __attribute__((address_space(1))) void*)src,
          (__attribute__((address_space(3))) void*)&Bl[pb][gbase * 64],
          16, 0, 0);
    }
  };

  // compute chunk in dbuf pb; PH=0: strips {r,z,i_n}; PH=1: strips {r,z,h_n}
  auto compute = [&](int pb, auto PH) {
    constexpr int ph = decltype(PH)::v;
    int g = lane >> 4, r = lane & 15;
#pragma unroll
    for (int t = 0; t < 2; t++) {
      int c16 = t * 4 + g;
      int gr = c16 ^ (r & 7);
      bf16x8 a[4], b[3][2];
#pragma unroll
      for (int f = 0; f < 4; f++) {
        int row = wr * 64 + f * 16 + r;
        a[f] = *(const bf16x8*)&Al[pb][(row * 8 + gr) * 8];
      }
#pragma unroll
      for (int st = 0; st < 3; st++)
#pragma unroll
        for (int cf = 0; cf < 2; cf++) {
          int gcol = st * 64 + wc * 32 + cf * 16 + r;
          b[st][cf] = *(const bf16x8*)&Bl[pb][(gcol * 8 + gr) * 8];
        }
      __builtin_amdgcn_s_setprio(1);
#pragma unroll
      for (int f = 0; f < 4; f++)
#pragma unroll
        for (int st = 0; st < 3; st++)
#pragma unroll
          for (int cf = 0; cf < 2; cf++) {
            constexpr int sm[2][3] = {{0, 1, 2}, {0, 1, 3}};
            acc[f][cf][sm[ph][st]] = __builtin_amdgcn_mfma_f32_16x16x32_bf16(
                a[f], b[st][cf], acc[f][cf][sm[ph][st]], 0, 0, 0);
          }
      __builtin_amdgcn_s_setprio(0);
    }
  };

  stage(0, 0);
  for (int c = 0; c < 28; ++c) {
    int cb = c & 1;
    if (c < 27) { stage(c + 1, cb ^ 1); WAITV(7); }
    else        { WAITV(0); }
    __builtin_amdgcn_s_barrier();              // chunk c staged for all waves
    if (c < 20) compute(cb, ic<0>{});
    else        compute(cb, ic<1>{});
    __builtin_amdgcn_s_barrier();              // WAR: buffer cb free to overwrite
  }

  // ---- GRU epilogue ----
  int g = lane >> 4, r = lane & 15;
#pragma unroll
  for (int cf = 0; cf < 2; cf++) {
    int cc = c0 + wc * 32 + cf * 16 + r;
    float br = b_ih[cc] + b_hh[cc];
    float bz = b_ih[512 + cc] + b_hh[512 + cc];
    float bin = b_ih[1024 + cc], bhn = b_hh[1024 + cc];
#pragma unroll
    for (int f = 0; f < 4; f++) {
      int rbase = row0 + wr * 64 + f * 16 + g * 4;
#pragma unroll
      for (int rr = 0; rr < 4; rr++) {
        int row = rbase + rr;
        if (row < N_NODES) {
          float rg = 1.f / (1.f + __expf(-(acc[f][cf][0][rr] + br)));
          float zg = 1.f / (1.f + __expf(-(acc[f][cf][1][rr] + bz)));
          float cd = tanhf(acc[f][cf][2][rr] + bin + rg * (acc[f][cf][3][rr] + bhn));
          float h = memory[(size_t)row * DIM_MEM + cc];
          float o = (counts[row] > 0) ? (1.f - zg) * cd + zg * h : h;
          out[(size_t)row * DIM_MEM + cc] = o;
        }
      }
    }
  }
}

// ---------------- launch ----------------
extern "C" void kernel_launch(void* const* d_in, const int* in_sizes, int n_in,
                              void* d_out, int out_size, void* d_ws, size_t ws_size,
                              hipStream_t stream) {
  const float* msg  = (const float*)d_in[0];
  const int*   seg  = (const int*)d_in[1];
  const float* mem  = (const float*)d_in[2];
  const float* W_ih = (const float*)d_in[3];
  const float* W_hh = (const float*)d_in[4];
  const float* b_ih = (const float*)d_in[5];
  const float* b_hh = (const float*)d_in[6];
  float* out = (float*)d_out;

  char* ws = (char*)d_ws;
  unsigned short* means = (unsigned short*)(ws);                     // 128,000,000 B
  unsigned short* memb  = (unsigned short*)(ws + 128000000LL);       //  51,200,000 B
  unsigned short* wihb  = (unsigned short*)(ws + 179200000LL);       //   3,932,160 B
  unsigned short* whhb  = (unsigned short*)(ws + 183132160LL);       //   1,572,864 B
  int* counts           = (int*)(ws + 184705024LL);                  //     200,000 B

  k_segmean<<<N_NODES, 64, 0, stream>>>(msg, seg, means, counts);
  k_cvt<<<(N_NODES * DIM_MEM / 4 + 255) / 256, 256, 0, stream>>>(mem, memb, N_NODES * DIM_MEM / 4);
  k_cvt<<<(3 * DIM_MEM * DIM_MSG / 4 + 255) / 256, 256, 0, stream>>>(W_ih, wihb, 3 * DIM_MEM * DIM_MSG / 4);
  k_cvt<<<(3 * DIM_MEM * DIM_MEM / 4 + 255) / 256, 256, 0, stream>>>(W_hh, whhb, 3 * DIM_MEM * DIM_MEM / 4);

  dim3 grid(8, (N_NODES + 255) / 256, 1);   // blockIdx.x = col-tile (L2/XCD-aligned)
  k_gru<<<grid, 512, 0, stream>>>(means, memb, wihb, whhb, b_ih, b_hh, mem, counts, out);
}

// Round 9
// 1396.212 us; speedup vs baseline: 1.0747x; 1.0747x over previous
//
#include <hip/hip_runtime.h>
#include <stdint.h>

#define N_NODES 50000
#define DIM_MEM 512
#define DIM_MSG 1280
#define N_MSG   100000

typedef __attribute__((ext_vector_type(8))) short bf16x8;
typedef __attribute__((ext_vector_type(4))) float f32x4;

template <int N> struct ic { static constexpr int v = N; };

// counted vmcnt wait; "memory" clobber orders all memory ops (ds_read/ds_write/
// global) across it -- no sched_barrier needed (that was only for reg-only MFMA
// vs lgkmcnt, rule #18), and omitting it lets the allocator shrink live ranges.
#define WAITV(n) asm volatile("s_waitcnt vmcnt(" #n ")" ::: "memory")

__device__ __forceinline__ unsigned short f2bf(float f) {
  union { float f; uint32_t u; } v; v.f = f;
  uint32_t u = v.u;
  u += 0x7fffu + ((u >> 16) & 1u);   // round-to-nearest-even
  return (unsigned short)(u >> 16);
}

// ---------------- kernel 1: segment mean (seg_ids sorted) ----------------
__global__ __launch_bounds__(64) void k_segmean(
    const float* __restrict__ msg, const int* __restrict__ seg,
    unsigned short* __restrict__ means, int* __restrict__ counts)
{
  int node = blockIdx.x;
  int lane = threadIdx.x;

  int lo = 0, hi = N_MSG;
  while (lo < hi) { int m = (lo + hi) >> 1; if (seg[m] < node) lo = m + 1; else hi = m; }
  int start = lo;
  hi = N_MSG;
  while (lo < hi) { int m = (lo + hi) >> 1; if (seg[m] < node + 1) lo = m + 1; else hi = m; }
  int end = lo;
  int cnt = end - start;
  if (lane == 0) counts[node] = cnt;

  float4 s[5];
#pragma unroll
  for (int j = 0; j < 5; j++) s[j] = make_float4(0.f, 0.f, 0.f, 0.f);
  const float4* m4 = (const float4*)msg;   // 320 float4 per row
  for (int r = start; r < end; r++) {
#pragma unroll
    for (int j = 0; j < 5; j++) {
      float4 v = m4[r * 320 + j * 64 + lane];
      s[j].x += v.x; s[j].y += v.y; s[j].z += v.z; s[j].w += v.w;
    }
  }
  float inv = (cnt > 0) ? 1.0f / (float)cnt : 0.0f;
  ushort4* o4 = (ushort4*)means;
#pragma unroll
  for (int j = 0; j < 5; j++) {
    ushort4 o;
    o.x = f2bf(s[j].x * inv); o.y = f2bf(s[j].y * inv);
    o.z = f2bf(s[j].z * inv); o.w = f2bf(s[j].w * inv);
    o4[node * 320 + j * 64 + lane] = o;
  }
}

// ---------------- kernel 2: f32 -> bf16 cast ----------------
__global__ __launch_bounds__(256) void k_cvt(
    const float* __restrict__ in, unsigned short* __restrict__ out, int n4)
{
  int i = blockIdx.x * 256 + threadIdx.x;
  if (i >= n4) return;
  float4 v = ((const float4*)in)[i];
  ushort4 o;
  o.x = f2bf(v.x); o.y = f2bf(v.y); o.z = f2bf(v.z); o.w = f2bf(v.w);
  ((ushort4*)out)[i] = o;
}

// ---------------- kernel 3: fused GEMM (4 strips) + GRU epilogue ----------------
// Block 128r x 64c, 4 waves (256 thr), wave = 64r x 32c:
//   acc[4][2][4 strips] = 128 f32/lane; launch_bounds(256,2) budgets 256
//   regs/thread -> 8 waves/CU = 2 blocks/CU (TLP across barriers).
//   LDS dbuf 2 x (A 16 KB + B 24 KB) = 80 KB -> exactly 2 blocks/CU.
// Per wave-chunk: 10 global_load_lds, 20 ds_read_b128, 48 MFMA
//   (LDS ~38 KB/MFLOP vs R7's 57).
// Schedule: stage(c+1) -> WAITV(10) (= chunk c landed, 10 flying) -> barrier
//   -> compute(c) -> barrier (WAR). Spill diet: b[3][2] read once per t,
//   a-frags streamed one at a time.
// 28 K-chunks: 0..19 = means@W_ih^T (K=1280), 20..27 = memb@W_hh^T (K=512).
__global__ __launch_bounds__(256, 2) void k_gru(
    const unsigned short* __restrict__ means, const unsigned short* __restrict__ memb,
    const unsigned short* __restrict__ wih,   const unsigned short* __restrict__ whh,
    const float* __restrict__ b_ih, const float* __restrict__ b_hh,
    const float* __restrict__ memory, const int* __restrict__ counts,
    float* __restrict__ out)
{
  __shared__ unsigned short Al[2][128 * 64];   // 2 x 16 KB
  __shared__ unsigned short Bl[2][192 * 64];   // 2 x 24 KB

  int tid = threadIdx.x;
  int lane = tid & 63, wid = tid >> 6;        // 4 waves
  int wr = wid >> 1, wc = wid & 1;            // 2 row-groups x 2 col-groups
  int row0 = blockIdx.y * 128;
  int c0 = blockIdx.x * 64;

  f32x4 acc[4][2][4];                          // [row-frag][col-frag][strip]
#pragma unroll
  for (int f = 0; f < 4; f++)
#pragma unroll
    for (int cf = 0; cf < 2; cf++)
#pragma unroll
      for (int s = 0; s < 4; s++) acc[f][cf][s] = (f32x4)(0.f);

  int lrow = lane >> 3;                        // row-within-8 for staging
  int csrc = (lane & 7) ^ lrow;                // inverse-swizzled source k-granule

  // stage chunk c into dbuf pb (4 A-loads + 6 B-loads per wave)
  auto stage = [&](int c, int pb) {
    const unsigned short* Ag; const unsigned short* Bg; int ld, k0;
    if (c < 20) { Ag = means; Bg = wih; ld = DIM_MSG; k0 = c * 64; }
    else        { Ag = memb;  Bg = whh; ld = DIM_MEM; k0 = (c - 20) * 64; }
#pragma unroll
    for (int i = 0; i < 4; i++) {              // A: 8 rows per load (rows 0..127)
      int rbase = (wid * 4 + i) * 8;
      int grow = row0 + rbase + lrow; if (grow > N_NODES - 1) grow = N_NODES - 1;
      const unsigned short* src = Ag + (size_t)grow * ld + k0 + csrc * 8;
      __builtin_amdgcn_global_load_lds(
          (const __attribute__((address_space(1))) void*)src,
          (__attribute__((address_space(3))) void*)&Al[pb][rbase * 64],
          16, 0, 0);
    }
#pragma unroll
    for (int i = 0; i < 6; i++) {              // B: 8 gate-cols per load (0..191)
      int gbase = (wid * 6 + i) * 8;
      int gcol = gbase + lrow;
      int st = gcol >> 6, col = gcol & 63;
      const unsigned short* src = Bg + (size_t)(st * 512 + c0 + col) * ld + k0 + csrc * 8;
      __builtin_amdgcn_global_load_lds(
          (const __attribute__((address_space(1))) void*)src,
          (__attribute__((address_space(3))) void*)&Bl[pb][gbase * 64],
          16, 0, 0);
    }
  };

  // compute chunk in dbuf pb; PH=0: strips {r,z,i_n}; PH=1: strips {r,z,h_n}
  auto compute = [&](int pb, auto PH) {
    constexpr int ph = decltype(PH)::v;
    int g = lane >> 4, r = lane & 15;
#pragma unroll
    for (int t = 0; t < 2; t++) {
      int c16 = t * 4 + g;
      int gr = c16 ^ (r & 7);
      bf16x8 b[3][2];
#pragma unroll
      for (int st = 0; st < 3; st++)
#pragma unroll
        for (int cf = 0; cf < 2; cf++) {
          int gcol = st * 64 + wc * 32 + cf * 16 + r;
          b[st][cf] = *(const bf16x8*)&Bl[pb][(gcol * 8 + gr) * 8];
        }
#pragma unroll
      for (int f = 0; f < 4; f++) {            // stream A one frag at a time
        int row = wr * 64 + f * 16 + r;
        bf16x8 a = *(const bf16x8*)&Al[pb][(row * 8 + gr) * 8];
        __builtin_amdgcn_s_setprio(1);
#pragma unroll
        for (int st = 0; st < 3; st++)
#pragma unroll
          for (int cf = 0; cf < 2; cf++) {
            constexpr int sm[2][3] = {{0, 1, 2}, {0, 1, 3}};
            acc[f][cf][sm[ph][st]] = __builtin_amdgcn_mfma_f32_16x16x32_bf16(
                a, b[st][cf], acc[f][cf][sm[ph][st]], 0, 0, 0);
          }
        __builtin_amdgcn_s_setprio(0);
      }
    }
  };

  stage(0, 0);
  for (int c = 0; c < 28; ++c) {
    int cb = c & 1;
    if (c < 27) { stage(c + 1, cb ^ 1); WAITV(10); }
    else        { WAITV(0); }
    __builtin_amdgcn_s_barrier();              // chunk c staged for all waves
    if (c < 20) compute(cb, ic<0>{});
    else        compute(cb, ic<1>{});
    __builtin_amdgcn_s_barrier();              // WAR: buffer cb free to overwrite
  }

  // ---- GRU epilogue ----
  int g = lane >> 4, r = lane & 15;
#pragma unroll
  for (int cf = 0; cf < 2; cf++) {
    int cc = c0 + wc * 32 + cf * 16 + r;
    float br = b_ih[cc] + b_hh[cc];
    float bz = b_ih[512 + cc] + b_hh[512 + cc];
    float bin = b_ih[1024 + cc], bhn = b_hh[1024 + cc];
#pragma unroll
    for (int f = 0; f < 4; f++) {
      int rbase = row0 + wr * 64 + f * 16 + g * 4;
#pragma unroll
      for (int rr = 0; rr < 4; rr++) {
        int row = rbase + rr;
        if (row < N_NODES) {
          float rg = 1.f / (1.f + __expf(-(acc[f][cf][0][rr] + br)));
          float zg = 1.f / (1.f + __expf(-(acc[f][cf][1][rr] + bz)));
          float cd = tanhf(acc[f][cf][2][rr] + bin + rg * (acc[f][cf][3][rr] + bhn));
          float h = memory[(size_t)row * DIM_MEM + cc];
          float o = (counts[row] > 0) ? (1.f - zg) * cd + zg * h : h;
          out[(size_t)row * DIM_MEM + cc] = o;
        }
      }
    }
  }
}

// ---------------- launch ----------------
extern "C" void kernel_launch(void* const* d_in, const int* in_sizes, int n_in,
                              void* d_out, int out_size, void* d_ws, size_t ws_size,
                              hipStream_t stream) {
  const float* msg  = (const float*)d_in[0];
  const int*   seg  = (const int*)d_in[1];
  const float* mem  = (const float*)d_in[2];
  const float* W_ih = (const float*)d_in[3];
  const float* W_hh = (const float*)d_in[4];
  const float* b_ih = (const float*)d_in[5];
  const float* b_hh = (const float*)d_in[6];
  float* out = (float*)d_out;

  char* ws = (char*)d_ws;
  unsigned short* means = (unsigned short*)(ws);                     // 128,000,000 B
  unsigned short* memb  = (unsigned short*)(ws + 128000000LL);       //  51,200,000 B
  unsigned short* wihb  = (unsigned short*)(ws + 179200000LL);       //   3,932,160 B
  unsigned short* whhb  = (unsigned short*)(ws + 183132160LL);       //   1,572,864 B
  int* counts           = (int*)(ws + 184705024LL);                  //     200,000 B

  k_segmean<<<N_NODES, 64, 0, stream>>>(msg, seg, means, counts);
  k_cvt<<<(N_NODES * DIM_MEM / 4 + 255) / 256, 256, 0, stream>>>(mem, memb, N_NODES * DIM_MEM / 4);
  k_cvt<<<(3 * DIM_MEM * DIM_MSG / 4 + 255) / 256, 256, 0, stream>>>(W_ih, wihb, 3 * DIM_MEM * DIM_MSG / 4);
  k_cvt<<<(3 * DIM_MEM * DIM_MEM / 4 + 255) / 256, 256, 0, stream>>>(W_hh, whhb, 3 * DIM_MEM * DIM_MEM / 4);

  dim3 grid(8, (N_NODES + 127) / 128, 1);   // blockIdx.x = col-tile (L2/XCD-aligned)
  k_gru<<<grid, 256, 0, stream>>>(means, memb, wihb, whhb, b_ih, b_hh, mem, counts, out);
}

// Round 12
// 599.248 us; speedup vs baseline: 2.5040x; 2.3299x over previous
//
#include <hip/hip_runtime.h>
#include <stdint.h>

#define N_NODES 50000
#define DIM_MEM 512
#define DIM_MSG 1280
#define N_MSG   100000

typedef __attribute__((ext_vector_type(8))) short bf16x8;
typedef __attribute__((ext_vector_type(4))) float f32x4;

template <int N> struct ic { static constexpr int v = N; };

__device__ __forceinline__ unsigned short f2bf(float f) {
  union { float f; uint32_t u; } v; v.f = f;
  uint32_t u = v.u;
  u += 0x7fffu + ((u >> 16) & 1u);   // round-to-nearest-even
  return (unsigned short)(u >> 16);
}

// ---------------- kernel 1: segment mean (seg_ids sorted) ----------------
__global__ __launch_bounds__(64) void k_segmean(
    const float* __restrict__ msg, const int* __restrict__ seg,
    unsigned short* __restrict__ means, int* __restrict__ counts)
{
  int node = blockIdx.x;
  int lane = threadIdx.x;

  int lo = 0, hi = N_MSG;
  while (lo < hi) { int m = (lo + hi) >> 1; if (seg[m] < node) lo = m + 1; else hi = m; }
  int start = lo;
  hi = N_MSG;
  while (lo < hi) { int m = (lo + hi) >> 1; if (seg[m] < node + 1) lo = m + 1; else hi = m; }
  int end = lo;
  int cnt = end - start;
  if (lane == 0) counts[node] = cnt;

  float4 s[5];
#pragma unroll
  for (int j = 0; j < 5; j++) s[j] = make_float4(0.f, 0.f, 0.f, 0.f);
  const float4* m4 = (const float4*)msg;   // 320 float4 per row
  for (int r = start; r < end; r++) {
#pragma unroll
    for (int j = 0; j < 5; j++) {
      float4 v = m4[r * 320 + j * 64 + lane];
      s[j].x += v.x; s[j].y += v.y; s[j].z += v.z; s[j].w += v.w;
    }
  }
  float inv = (cnt > 0) ? 1.0f / (float)cnt : 0.0f;
  ushort4* o4 = (ushort4*)means;
#pragma unroll
  for (int j = 0; j < 5; j++) {
    ushort4 o;
    o.x = f2bf(s[j].x * inv); o.y = f2bf(s[j].y * inv);
    o.z = f2bf(s[j].z * inv); o.w = f2bf(s[j].w * inv);
    o4[node * 320 + j * 64 + lane] = o;
  }
}

// ---------------- kernel 2: f32 -> bf16 cast ----------------
__global__ __launch_bounds__(256) void k_cvt(
    const float* __restrict__ in, unsigned short* __restrict__ out, int n4)
{
  int i = blockIdx.x * 256 + threadIdx.x;
  if (i >= n4) return;
  float4 v = ((const float4*)in)[i];
  ushort4 o;
  o.x = f2bf(v.x); o.y = f2bf(v.y); o.z = f2bf(v.z); o.w = f2bf(v.w);
  ((ushort4*)out)[i] = o;
}

// ---------------- kernel 3: fused GEMM (4 strips) + GRU epilogue ----------------
// R7 geometry (known good: 402 us, VGPR 64, no spill, 3 blocks/CU):
//   256 thr / 4 waves; tile 64 rows x 64 cols; wave = 64r x 16c x 3 strips;
//   acc[4][4] = 64 f32; single-buffered 32 KB LDS; plain 2-barrier loop.
// Phase-split loops: compile-time ld per phase (no per-chunk select / runtime
// multiply); per-chunk source advance = 32-bit per-lane offset += 64 elements
// from a uniform base (compiler emits saddr-form global_load_lds).
// NOTE (R11 lesson): global_load_lds's imm-offset arg applies to BOTH the
// global and LDS address (LLVM IntrinsicsAMDGPU.td) -- unusable for
// source-only advance; keep offset arg = 0.
// LDS layout (R6-proven): row-major [row][64k] + XOR swizzle c16^=(row&7);
// staging source permutes k-granule (csrc = (lane&7)^lrow) -> fully coalesced.
__global__ __launch_bounds__(256, 3) void k_gru(
    const unsigned short* __restrict__ means, const unsigned short* __restrict__ memb,
    const unsigned short* __restrict__ wih,   const unsigned short* __restrict__ whh,
    const float* __restrict__ b_ih, const float* __restrict__ b_hh,
    const float* __restrict__ memory, const int* __restrict__ counts,
    float* __restrict__ out)
{
  __shared__ unsigned short Al[64 * 64];    // 8 KB
  __shared__ unsigned short Bl[192 * 64];   // 24 KB

  int tid = threadIdx.x;
  int lane = tid & 63, wid = tid >> 6;       // 4 waves
  int wc = wid;                               // col-group 0..3
  int row0 = blockIdx.y * 64;
  int c0 = blockIdx.x * 64;

  f32x4 acc[4][4];                            // [row-frag][strip]: r, z, i_n, h_n
#pragma unroll
  for (int f = 0; f < 4; f++)
#pragma unroll
    for (int s = 0; s < 4; s++) acc[f][s] = (f32x4)(0.f);

  int lrow = lane >> 3;                       // row-within-8 for staging
  int csrc = (lane & 7) ^ lrow;               // inverse-swizzled source k-granule

  // A-row / B-row handled by this lane for each of its loads (phase-invariant)
  int arow[2], brow[6]; uint32_t adst[2], bdst[6];
#pragma unroll
  for (int i = 0; i < 2; i++) {
    int rbase = (wid * 2 + i) * 8;
    int grow = row0 + rbase + lrow; if (grow > N_NODES - 1) grow = N_NODES - 1;
    arow[i] = grow; adst[i] = rbase * 64;
  }
#pragma unroll
  for (int i = 0; i < 6; i++) {
    int gbase = (wid * 6 + i) * 8;
    int gcol = gbase + lrow;                  // 0..191
    int st = gcol >> 6, col = gcol & 63;
    brow[i] = st * 512 + c0 + col; bdst[i] = gbase * 64;
  }

  // compute current chunk; PH=0: strips {0,1,2}; PH=1: strips {0,1,3}
  auto compute = [&](auto PH) {
    constexpr int ph = decltype(PH)::v;
    int g = lane >> 4, r = lane & 15;
#pragma unroll
    for (int t = 0; t < 2; t++) {
      int c16 = t * 4 + g;
      int gr = c16 ^ (r & 7);
      bf16x8 a[4], b[3];
#pragma unroll
      for (int f = 0; f < 4; f++) {
        int row = f * 16 + r;
        a[f] = *(const bf16x8*)&Al[(row * 8 + gr) * 8];
      }
#pragma unroll
      for (int st = 0; st < 3; st++) {
        int gcol = st * 64 + wc * 16 + r;
        b[st] = *(const bf16x8*)&Bl[(gcol * 8 + gr) * 8];
      }
#pragma unroll
      for (int f = 0; f < 4; f++)
#pragma unroll
        for (int st = 0; st < 3; st++) {
          constexpr int sm[2][3] = {{0, 1, 2}, {0, 1, 3}};
          acc[f][sm[ph][st]] = __builtin_amdgcn_mfma_f32_16x16x32_bf16(
              a[f], b[st], acc[f][sm[ph][st]], 0, 0, 0);
        }
    }
  };

  // ---- phase 1: means @ W_ih^T (K=1280, 20 chunks), strips {r, z, i_n} ----
  {
    uint32_t aoff[2], boff[6];
#pragma unroll
    for (int i = 0; i < 2; i++) aoff[i] = (uint32_t)(arow[i] * DIM_MSG + csrc * 8);
#pragma unroll
    for (int i = 0; i < 6; i++) boff[i] = (uint32_t)(brow[i] * DIM_MSG + csrc * 8);
    for (int c = 0; c < 20; ++c) {
#pragma unroll
      for (int i = 0; i < 2; i++) {
        __builtin_amdgcn_global_load_lds(
            (const __attribute__((address_space(1))) void*)(means + aoff[i]),
            (__attribute__((address_space(3))) void*)&Al[adst[i]],
            16, 0, 0);
        aoff[i] += 64;
      }
#pragma unroll
      for (int i = 0; i < 6; i++) {
        __builtin_amdgcn_global_load_lds(
            (const __attribute__((address_space(1))) void*)(wih + boff[i]),
            (__attribute__((address_space(3))) void*)&Bl[bdst[i]],
            16, 0, 0);
        boff[i] += 64;
      }
      __syncthreads();
      compute(ic<0>{});
      __syncthreads();
    }
  }
  // ---- phase 2: memb @ W_hh^T (K=512, 8 chunks), strips {r, z, h_n} ----
  {
    uint32_t aoff[2], boff[6];
#pragma unroll
    for (int i = 0; i < 2; i++) aoff[i] = (uint32_t)(arow[i] * DIM_MEM + csrc * 8);
#pragma unroll
    for (int i = 0; i < 6; i++) boff[i] = (uint32_t)(brow[i] * DIM_MEM + csrc * 8);
    for (int c = 0; c < 8; ++c) {
#pragma unroll
      for (int i = 0; i < 2; i++) {
        __builtin_amdgcn_global_load_lds(
            (const __attribute__((address_space(1))) void*)(memb + aoff[i]),
            (__attribute__((address_space(3))) void*)&Al[adst[i]],
            16, 0, 0);
        aoff[i] += 64;
      }
#pragma unroll
      for (int i = 0; i < 6; i++) {
        __builtin_amdgcn_global_load_lds(
            (const __attribute__((address_space(1))) void*)(whh + boff[i]),
            (__attribute__((address_space(3))) void*)&Bl[bdst[i]],
            16, 0, 0);
        boff[i] += 64;
      }
      __syncthreads();
      compute(ic<1>{});
      __syncthreads();
    }
  }

  // ---- GRU epilogue ----
  int cc = c0 + wc * 16 + (lane & 15);
  float br = b_ih[cc] + b_hh[cc];
  float bz = b_ih[512 + cc] + b_hh[512 + cc];
  float bin = b_ih[1024 + cc], bhn = b_hh[1024 + cc];
  int g = lane >> 4;
#pragma unroll
  for (int f = 0; f < 4; f++) {
    int rbase = row0 + f * 16 + g * 4;
#pragma unroll
    for (int rr = 0; rr < 4; rr++) {
      int row = rbase + rr;
      if (row < N_NODES) {
        float rg = 1.f / (1.f + __expf(-(acc[f][0][rr] + br)));
        float zg = 1.f / (1.f + __expf(-(acc[f][1][rr] + bz)));
        float cd = tanhf(acc[f][2][rr] + bin + rg * (acc[f][3][rr] + bhn));
        float h = memory[(size_t)row * DIM_MEM + cc];
        float o = (counts[row] > 0) ? (1.f - zg) * cd + zg * h : h;
        out[(size_t)row * DIM_MEM + cc] = o;
      }
    }
  }
}

// ---------------- launch ----------------
extern "C" void kernel_launch(void* const* d_in, const int* in_sizes, int n_in,
                              void* d_out, int out_size, void* d_ws, size_t ws_size,
                              hipStream_t stream) {
  const float* msg  = (const float*)d_in[0];
  const int*   seg  = (const int*)d_in[1];
  const float* mem  = (const float*)d_in[2];
  const float* W_ih = (const float*)d_in[3];
  const float* W_hh = (const float*)d_in[4];
  const float* b_ih = (const float*)d_in[5];
  const float* b_hh = (const float*)d_in[6];
  float* out = (float*)d_out;

  char* ws = (char*)d_ws;
  unsigned short* means = (unsigned short*)(ws);                     // 128,000,000 B
  unsigned short* memb  = (unsigned short*)(ws + 128000000LL);       //  51,200,000 B
  unsigned short* wihb  = (unsigned short*)(ws + 179200000LL);       //   3,932,160 B
  unsigned short* whhb  = (unsigned short*)(ws + 183132160LL);       //   1,572,864 B
  int* counts           = (int*)(ws + 184705024LL);                  //     200,000 B

  k_segmean<<<N_NODES, 64, 0, stream>>>(msg, seg, means, counts);
  k_cvt<<<(N_NODES * DIM_MEM / 4 + 255) / 256, 256, 0, stream>>>(mem, memb, N_NODES * DIM_MEM / 4);
  k_cvt<<<(3 * DIM_MEM * DIM_MSG / 4 + 255) / 256, 256, 0, stream>>>(W_ih, wihb, 3 * DIM_MEM * DIM_MSG / 4);
  k_cvt<<<(3 * DIM_MEM * DIM_MEM / 4 + 255) / 256, 256, 0, stream>>>(W_hh, whhb, 3 * DIM_MEM * DIM_MEM / 4);

  dim3 grid(8, (N_NODES + 63) / 64, 1);   // blockIdx.x = col-tile (L2/XCD-aligned)
  k_gru<<<grid, 256, 0, stream>>>(means, memb, wihb, whhb, b_ih, b_hh, mem, counts, out);
}